// Round 7
// baseline (944.198 us; speedup 1.0000x reference)
//
#include <hip/hip_runtime.h>
#include <hip/hip_bf16.h>

#define EPS       0.05f
#define N_ITERS   20
#define NR        8192      // N == M
#define DIM       64
#define LOG2E     1.4426950408889634f
#define LN2       0.6931471805599453f
#define S2        (2.0f * LOG2E / EPS)   // 57.7078...
#define EPSLN2    (EPS * LN2)
#define NEGINF    (-1e30f)
#define NSPLIT    4                      // column splits (partials per side)

typedef __attribute__((ext_vector_type(8))) short short8;
typedef __attribute__((ext_vector_type(4))) float float4v;

__device__ __forceinline__ float wave_reduce_sum(float v) {
    #pragma unroll
    for (int m = 1; m < 64; m <<= 1) v += __shfl_xor(v, m, 64);
    return v;
}

// log2-LSE merge of 4 partials
__device__ __forceinline__ float merge4_l(float2 p0, float2 p1, float2 p2, float2 p3) {
    float M = fmaxf(fmaxf(p0.x, p1.x), fmaxf(p2.x, p3.x));
    float S = p0.y * __builtin_amdgcn_exp2f(p0.x - M)
            + p1.y * __builtin_amdgcn_exp2f(p1.x - M)
            + p2.y * __builtin_amdgcn_exp2f(p2.x - M)
            + p3.y * __builtin_amdgcn_exp2f(p3.x - M);
    return M + __builtin_amdgcn_logf(S);   // log2 domain
}

// ---- setup: sums of a and b ------------------------------------------------
__global__ void sums_kernel(const float* __restrict__ a, const float* __restrict__ b,
                            float* __restrict__ sums) {
    __shared__ float red[32];
    int tid = threadIdx.x;
    float pa = 0.f, pb = 0.f;
    for (int i = tid; i < NR; i += blockDim.x) { pa += a[i]; pb += b[i]; }
    pa = wave_reduce_sum(pa);
    pb = wave_reduce_sum(pb);
    int wid = tid >> 6, ln = tid & 63;
    if (ln == 0) { red[wid] = pa; red[wid + 16] = pb; }
    __syncthreads();
    if (tid == 0) {
        float sa = 0.f, sb = 0.f;
        int nw = blockDim.x >> 6;
        for (int w = 0; w < nw; w++) { sa += red[w]; sb += red[w + 16]; }
        sums[0] = logf(sa); sums[1] = logf(sb); sums[2] = sa; sums[3] = sb;
    }
}

// ---- setup: bf16 copies (row-major + MFMA-stream layout), norms, weights ---
// thread = one 16B chunk: cid = row*8 + c  (c = k-chunk 0..7)
__global__ void prep_kernel(const float* __restrict__ x, const float* __restrict__ y,
                            const float* __restrict__ a, const float* __restrict__ b,
                            const float* __restrict__ sums,
                            short8* __restrict__ xr, short8* __restrict__ yr,
                            short8* __restrict__ xs, short8* __restrict__ ys,
                            float* __restrict__ x2, float* __restrict__ y2,
                            float* __restrict__ la2, float* __restrict__ lb2,
                            float2* __restrict__ Pb) {   // [NSPLIT][NR] g-partials
    int gid = blockIdx.x * 256 + threadIdx.x;
    bool isx = gid < NR * 8;
    int cid = isx ? gid : gid - NR * 8;
    int row = cid >> 3;
    int c   = cid & 7;
    const float4* src = (const float4*)(isx ? x : y);
    float4 v0 = src[row * 16 + c * 2];
    float4 v1 = src[row * 16 + c * 2 + 1];

    short8 st;
    st[0] = __bfloat16_as_short(__float2bfloat16(v0.x));
    st[1] = __bfloat16_as_short(__float2bfloat16(v0.y));
    st[2] = __bfloat16_as_short(__float2bfloat16(v0.z));
    st[3] = __bfloat16_as_short(__float2bfloat16(v0.w));
    st[4] = __bfloat16_as_short(__float2bfloat16(v1.x));
    st[5] = __bfloat16_as_short(__float2bfloat16(v1.y));
    st[6] = __bfloat16_as_short(__float2bfloat16(v1.z));
    st[7] = __bfloat16_as_short(__float2bfloat16(v1.w));

    (isx ? xr : yr)[row * 8 + c] = st;                       // row-major
    int T = row >> 4, ln = row & 15, f = c >> 2, q = c & 3;
    (isx ? xs : ys)[T * 128 + f * 64 + q * 16 + ln] = st;    // stream layout

    float sq = v0.x*v0.x + v0.y*v0.y + v0.z*v0.z + v0.w*v0.w
             + v1.x*v1.x + v1.y*v1.y + v1.z*v1.z + v1.w*v1.w;
    #pragma unroll
    for (int m = 1; m < 8; m <<= 1) sq += __shfl_xor(sq, m, 64);

    if (c == 0) {
        if (isx) {
            x2[row] = sq;
            la2[row] = (logf(a[row]) - sums[0]) * LOG2E;
        } else {
            y2[row] = sq;
            lb2[row] = (logf(b[row]) - sums[1]) * LOG2E;
            Pb[row] = make_float2(sq * (LOG2E / EPS), 1.0f);   // g = 0 initially
            #pragma unroll
            for (int k = 1; k < NSPLIT; k++)
                Pb[k * NR + row] = make_float2(NEGINF, 0.0f);
        }
    }
}

// 4-wide online LSE update: one state, 4 new z's
#define LSE4(acc, c4, mm, ss)                                            \
    {                                                                    \
        float z0 = fmaf(S2, (acc)[0], (c4).x);                           \
        float z1 = fmaf(S2, (acc)[1], (c4).y);                           \
        float z2 = fmaf(S2, (acc)[2], (c4).z);                           \
        float z3 = fmaf(S2, (acc)[3], (c4).w);                           \
        float zm = fmaxf(fmaxf(z0, z1), fmaxf(z2, z3));                  \
        float mn = fmaxf((mm), zm);                                      \
        float e  = __builtin_amdgcn_exp2f((mm) - mn);                    \
        float p  = (__builtin_amdgcn_exp2f(z0 - mn)                      \
                  + __builtin_amdgcn_exp2f(z1 - mn))                     \
                 + (__builtin_amdgcn_exp2f(z2 - mn)                      \
                  + __builtin_amdgcn_exp2f(z3 - mn));                    \
        (ss) = fmaf((ss), e, p);                                         \
        (mm) = mn;                                                       \
    }

// ---- one softmin sweep (quarter of the columns) ----------------------------
// R7: 128 rows/block (2x reuse vs R6) + paired-wave L1 sharing: 16 waves =
// 8 col-strips x 2 row-halves; waves (w, w+8) stream the SAME 32KB Y-strip in
// lock-step so the second wave's requests hit L1 / merge on the miss path.
// Grid: 256 blocks = 64 row-groups x 4 col-quarters. 1024 thr = 16 waves.
__global__ __launch_bounds__(1024, 4) void pass_kernel(
        const short8* __restrict__ matXr,   // row-major resident (rows)
        const short8* __restrict__ matYs,   // stream-layout streamed (cols)
        const float2* __restrict__ Pin,     // [NSPLIT][NR] column-side partials
        const float* __restrict__ lw2col,   // [NR]
        float2* __restrict__ Pout) {        // [NSPLIT][NR] row-side partials
    __shared__ __attribute__((aligned(16))) float cbl[2048];
    __shared__ float2 comb[128][9];         // [row][strip] (+1 pad)

    const int tid = threadIdx.x;
    const int bi  = blockIdx.x;
    const int q4  = bi & 3;                 // column quarter
    const int rb  = (bi >> 2) * 128;        // first row
    const int cb0 = q4 * 2048;              // first column

    // ---- prologue: merge 4 column partials -> cb for this block's 2048 cols
    {
        int j = cb0 + tid * 2;              // two columns per thread
        float4 p0 = *(const float4*)(Pin + 0 * NR + j);
        float4 p1 = *(const float4*)(Pin + 1 * NR + j);
        float4 p2 = *(const float4*)(Pin + 2 * NR + j);
        float4 p3 = *(const float4*)(Pin + 3 * NR + j);
        float2 lw = *(const float2*)(lw2col + j);
        float2 cb;
        cb.x = lw.x - merge4_l(make_float2(p0.x, p0.y), make_float2(p1.x, p1.y),
                               make_float2(p2.x, p2.y), make_float2(p3.x, p3.y));
        cb.y = lw.y - merge4_l(make_float2(p0.z, p0.w), make_float2(p1.z, p1.w),
                               make_float2(p2.z, p2.w), make_float2(p3.z, p3.w));
        *(float2*)(cbl + tid * 2) = cb;
    }

    const int w     = tid >> 6;       // wave 0..15
    const int lane  = tid & 63;
    const int quad  = lane >> 4;
    const int ln    = lane & 15;
    const int strip = w & 7;          // 256-col strip within the quarter
    const int rh    = w >> 3;         // row half (64 rows)

    // resident X fragments (B-operand): 4 row-tiles, rows rb + rh*64 + t*16 + ln
    short8 xf0[4], xf1[4];
    #pragma unroll
    for (int t = 0; t < 4; t++) {
        int r = rb + rh * 64 + t * 16 + ln;
        xf0[t] = matXr[r * 8 + quad];
        xf1[t] = matXr[r * 8 + quad + 4];
    }

    // streamed Y (A-operand), stream layout: tile T at matYs[T*128 + lane]
    const int T0 = q4 * 128 + strip * 16;
    const short8* yp = matYs + (size_t)T0 * 128 + lane;
    const float* cbs = cbl + strip * 256 + quad * 4;

    float m[4], s[4];
    #pragma unroll
    for (int t = 0; t < 4; t++) { m[t] = NEGINF; s[t] = 0.f; }

    __syncthreads();   // cbl ready

    #pragma unroll 2
    for (int jt = 0; jt < 16; jt++) {
        short8 ya0 = yp[0];
        short8 ya1 = yp[64];
        float4 c4  = *(const float4*)(cbs + jt * 16);
        yp += 128;

        float4v acc[4];
        #pragma unroll
        for (int t = 0; t < 4; t++) {
            float4v z = {0.f, 0.f, 0.f, 0.f};
            z = __builtin_amdgcn_mfma_f32_16x16x32_bf16(ya0, xf0[t], z, 0, 0, 0);
            z = __builtin_amdgcn_mfma_f32_16x16x32_bf16(ya1, xf1[t], z, 0, 0, 0);
            acc[t] = z;
        }
        #pragma unroll
        for (int t = 0; t < 4; t++) LSE4(acc[t], c4, m[t], s[t]);
    }

    // combine across the 4 quads (same ln = same output rows)
    #pragma unroll
    for (int mask = 16; mask < 64; mask <<= 1) {
        #pragma unroll
        for (int t = 0; t < 4; t++) {
            float mo = __shfl_xor(m[t], mask, 64);
            float so = __shfl_xor(s[t], mask, 64);
            float M  = fmaxf(m[t], mo);
            s[t] = s[t] * __builtin_amdgcn_exp2f(m[t] - M)
                 + so   * __builtin_amdgcn_exp2f(mo   - M);
            m[t] = M;
        }
    }

    if (lane < 16) {
        #pragma unroll
        for (int t = 0; t < 4; t++)
            comb[rh * 64 + t * 16 + ln][strip] = make_float2(m[t], s[t]);
    }
    __syncthreads();

    // merge the 8 strips per row; write this quarter's partial
    if (tid < 128) {
        float2 c = comb[tid][0];
        float M = c.x, S = c.y;
        #pragma unroll
        for (int cc = 1; cc < 8; cc++) {
            float2 p = comb[tid][cc];
            float Mn = fmaxf(M, p.x);
            S = S * __builtin_amdgcn_exp2f(M - Mn)
              + p.y * __builtin_amdgcn_exp2f(p.x - Mn);
            M = Mn;
        }
        Pout[q4 * NR + rb + tid] = make_float2(M, S);
    }
}

// ---- final reduction: <a, f_fin>/sa + <b, g_fin>/sb ------------------------
__global__ void reduce_kernel(const float* __restrict__ a, const float* __restrict__ b,
                              const float* __restrict__ sums,
                              const float* __restrict__ x2, const float* __restrict__ y2,
                              const float2* __restrict__ Pff, const float2* __restrict__ Pgf,
                              float* __restrict__ out) {
    __shared__ float red[32];
    int tid = threadIdx.x;
    float da = 0.f, db = 0.f;
    for (int i = tid; i < NR; i += blockDim.x) {
        float fv = x2[i] - EPSLN2 * merge4_l(Pff[i], Pff[NR + i],
                                             Pff[2 * NR + i], Pff[3 * NR + i]);
        float gv = y2[i] - EPSLN2 * merge4_l(Pgf[i], Pgf[NR + i],
                                             Pgf[2 * NR + i], Pgf[3 * NR + i]);
        da += a[i] * fv;
        db += b[i] * gv;
    }
    da = wave_reduce_sum(da);
    db = wave_reduce_sum(db);
    int wid = tid >> 6, ln = tid & 63;
    if (ln == 0) { red[wid] = da; red[wid + 16] = db; }
    __syncthreads();
    if (tid == 0) {
        float DA = 0.f, DB = 0.f;
        int nw = blockDim.x >> 6;
        for (int w = 0; w < nw; w++) { DA += red[w]; DB += red[w + 16]; }
        out[0] = DA / sums[2] + DB / sums[3];
    }
}

extern "C" void kernel_launch(void* const* d_in, const int* in_sizes, int n_in,
                              void* d_out, int out_size, void* d_ws, size_t ws_size,
                              hipStream_t stream) {
    const float* a = (const float*)d_in[0];
    const float* x = (const float*)d_in[1];
    const float* b = (const float*)d_in[2];
    const float* y = (const float*)d_in[3];

    char* ws = (char*)d_ws;
    short8* xr = (short8*)ws;                        // 1 MB row-major
    short8* yr = (short8*)(ws + (1 << 20));          // 1 MB
    short8* xs = (short8*)(ws + (2 << 20));          // 1 MB stream layout
    short8* ys = (short8*)(ws + (3 << 20));          // 1 MB
    float* fp  = (float*)(ws + (4 << 20));
    float* x2  = fp;
    float* y2  = fp + NR;
    float* la2 = fp + 2 * NR;
    float* lb2 = fp + 3 * NR;
    float2* P   = (float2*)(fp + 4 * NR);
    float2* Pf  = P;                          // f-side partials [NSPLIT][NR]
    float2* Pb  = P + NSPLIT * NR;            // g-side partials
    float2* Pff = P + 2 * NSPLIT * NR;        // final f partials
    float2* Pgf = P + 3 * NSPLIT * NR;        // final g partials
    float* sums = (float*)(P + 4 * NSPLIT * NR);

    sums_kernel<<<1, 1024, 0, stream>>>(a, b, sums);
    prep_kernel<<<(2 * NR * 8) / 256, 256, 0, stream>>>(x, y, a, b, sums,
                                                        xr, yr, xs, ys,
                                                        x2, y2, la2, lb2, Pb);

    for (int it = 0; it < N_ITERS; it++) {
        // f-update: rows = x-side (row-major), cols = y-side (stream)
        pass_kernel<<<256, 1024, 0, stream>>>(xr, ys, Pb, lb2, Pf);
        // g-update: rows = y-side, cols = x-side
        pass_kernel<<<256, 1024, 0, stream>>>(yr, xs, Pf, la2, Pb);
    }
    // final symmetric update from detached potentials
    pass_kernel<<<256, 1024, 0, stream>>>(xr, ys, Pb, lb2, Pff);
    pass_kernel<<<256, 1024, 0, stream>>>(yr, xs, Pf, la2, Pgf);

    reduce_kernel<<<1, 1024, 0, stream>>>(a, b, sums, x2, y2, Pff, Pgf, (float*)d_out);
}